// Round 13
// baseline (178.340 us; speedup 1.0000x reference)
//
#include <hip/hip_runtime.h>

#define N_NODES 100000
#define N_EDGES 1600000
#define DIM 128
#define NH 4

#define NPB 512                                   // nodes per coarse bucket
#define NB 196                                    // buckets with dst>>9 < 196
#define CAP 12288                                 // padded bucket capacity (mean 8192)
#define BCHUNK 8192                               // edges per scatter block
#define BEPT 32                                   // BCHUNK / 256
#define NBLK 196                                  // scatter blocks
#define CVT_BLKS 256                              // prep (convert+pack) blocks
#define GB 25000                                  // gather blocks (4 nodes each)
#define SMB 1563                                  // self-mm / final blocks (64 nodes)
#define FUSED_GRID (17 * SMB)                     // 26571; every 17th block = self-mm

typedef __attribute__((ext_vector_type(8))) short bf16x8;
typedef __attribute__((ext_vector_type(4))) float f32x4;
typedef __attribute__((ext_vector_type(8))) unsigned short u16x8;

// ws layout, BYTE offsets:
//   bcur   : [0, 1024)           int[256] RELATIVE bucket cursors (memset 0)
//   rowoff : [4096, 404096)      int[100000] packed (csr_lo<<9)|deg
//   csr    : [405504, 6805504)   int[1.6M] src ids, dense, bucketed+sorted by dst
//   wpack  : [6805504, 6871040)  bf16 MFMA-packed Ws|Wn
//   bavg   : [6871040, 6871552)  f32[128]
//   hb     : [6871552, 32471552) bf16 copy of h (25.6MB)
// ebuf (padded buckets, 256*CAP ints = 12.6MB) lives in d_out: dead before gather.
// During the fused dispatch, each 512B out row = [hn bf16 256B | selfbuf 256B]:
// disjoint 128B cachelines, written by different blocks, read by final_gemm.
#define B_BCUR   0u
#define B_ROWOFF 4096u
#define B_CSR    405504u
#define B_WPACK  6805504u
#define B_BAVG   6871040u
#define B_HB     6871552u
#define NEED_BF16 32869376ull

// branchless RTNE f32->bf16 (finite inputs; no NaN path)
__device__ inline unsigned short f2bf(float x) {
    union { float f; unsigned u; } v; v.f = x;
    unsigned r = v.u + 0x7fffu + ((v.u >> 16) & 1u);
    return (unsigned short)(r >> 16);
}

// ---------------------------------------------------------------------------
// MERGED prep + bucket scatter. Blocks [0,NBLK): single-pass bucket scatter
// (relative cursors). Blocks [NBLK, NBLK+CVT_BLKS): weight pack + bavg +
// (BF) grid-stride h->bf16 conversion. Independent work, one dispatch.
// ---------------------------------------------------------------------------
template <bool BF>
__global__ __launch_bounds__(256) void prep_scatter_kernel(
    const int* __restrict__ src, const int* __restrict__ dst,
    int* __restrict__ bcur, int* __restrict__ ebuf,
    const float* __restrict__ h, unsigned short* __restrict__ hb,
    const float* __restrict__ Ws, const float* __restrict__ Wn,
    const float* __restrict__ b, unsigned short* __restrict__ wpack,
    float* __restrict__ bavg) {
    const int t = threadIdx.x;
    if (blockIdx.x >= NBLK) {
        // ---- prep path ----
        const int pb = blockIdx.x - NBLK;
        int i = pb * 256 + t;
        if (i < DIM * DIM) {
            float s = 0.f, n = 0.f;
#pragma unroll
            for (int hh = 0; hh < NH; ++hh) {
                s += Ws[hh * DIM * DIM + i];
                n += Wn[hh * DIM * DIM + i];
            }
            s *= 0.25f; n *= 0.25f;
            int k = i >> 7, o = i & 127;
            int nt = o >> 4, lanelo = o & 15;
            int ks = k >> 5, lanehi = (k & 31) >> 3, e = k & 7;
            int pos = (((nt * 4 + ks) * 64) + lanehi * 16 + lanelo) * 8 + e;
            wpack[pos] = f2bf(s);
            wpack[16384 + pos] = f2bf(n);
        }
        if (i < DIM) {
            float bb = 0.f;
#pragma unroll
            for (int hh = 0; hh < NH; ++hh) bb += b[hh * DIM + i];
            bavg[i] = 0.25f * bb;
        }
        if (BF) {  // grid-stride bf16 conversion: 1.6M 8-elem chunks
            for (int c8 = i; c8 < N_NODES * DIM / 8; c8 += CVT_BLKS * 256) {
                const float4* p = reinterpret_cast<const float4*>(h) + (size_t)c8 * 2;
                float4 a = p[0], c = p[1];
                u16x8 r;
                r[0] = f2bf(a.x); r[1] = f2bf(a.y); r[2] = f2bf(a.z); r[3] = f2bf(a.w);
                r[4] = f2bf(c.x); r[5] = f2bf(c.y); r[6] = f2bf(c.z); r[7] = f2bf(c.w);
                reinterpret_cast<u16x8*>(hb)[c8] = r;
            }
        }
        return;
    }
    // ---- scatter path ----
    __shared__ int stage[BCHUNK];
    __shared__ unsigned char bkt[BCHUNK];
    __shared__ int lc[256], lbase[256], lpos[256];
    lc[t] = 0;
    lpos[t] = 0;
    __syncthreads();
    int e0 = blockIdx.x * BCHUNK;
#pragma unroll 4
    for (int j = 0; j < BEPT; ++j) {
        int e = e0 + j * 256 + t;
        if (e < N_EDGES) {
            int d = dst[e];
            stage[j * 256 + t] = (src[e] << 9) | (d & (NPB - 1));
            bkt[j * 256 + t] = (unsigned char)(d >> 9);
            atomicAdd(&lc[d >> 9], 1);
        }
    }
    __syncthreads();
    if (lc[t]) lbase[t] = t * CAP + atomicAdd(&bcur[t], lc[t]);  // relative cursors
    __syncthreads();
#pragma unroll 4
    for (int j = 0; j < BEPT; ++j) {
        int e = e0 + j * 256 + t;
        if (e < N_EDGES) {
            int bb = bkt[j * 256 + t];
            int o = atomicAdd(&lpos[bb], 1);
            ebuf[lbase[bb] + o] = stage[j * 256 + t];
        }
    }
}

// ---------------------------------------------------------------------------
// one block per bucket: internal 256-bucket scan, local 512-slot hist + scan
// -> packed rowoff ((lo<<9)|deg), then scatter src into the dense csr window.
// ---------------------------------------------------------------------------
__global__ __launch_bounds__(256) void csr_build_kernel(const int* __restrict__ bcur,
                                                        const int* __restrict__ ebuf,
                                                        int* __restrict__ rowoff,
                                                        int* __restrict__ csr) {
    __shared__ int hh[NPB], off[NPB], cur[NPB], ss[256];
    int b = blockIdx.x, t = threadIdx.x;
    int cnt = bcur[b];           // relative count
    int ibase = b * CAP;
    ss[t] = bcur[t];
    __syncthreads();
    for (int o = 1; o < 256; o <<= 1) {
        int add = (t >= o) ? ss[t - o] : 0;
        __syncthreads();
        ss[t] += add;
        __syncthreads();
    }
    int obase = ss[b] - cnt;
    hh[t] = 0; hh[t + 256] = 0;
    cur[t] = 0; cur[t + 256] = 0;
    __syncthreads();
    for (int i = t; i < cnt; i += 256) atomicAdd(&hh[ebuf[ibase + i] & (NPB - 1)], 1);
    __syncthreads();
    int e0 = hh[2 * t], e1 = hh[2 * t + 1];
    ss[t] = e0 + e1;
    __syncthreads();
    for (int o = 1; o < 256; o <<= 1) {
        int add = (t >= o) ? ss[t - o] : 0;
        __syncthreads();
        ss[t] += add;
        __syncthreads();
    }
    int ex = ss[t] - (e0 + e1);
    off[2 * t] = ex;
    off[2 * t + 1] = ex + e0;
    __syncthreads();
    int n0 = b * NPB;
#pragma unroll
    for (int k = 0; k < 2; ++k) {
        int s2 = 2 * t + k;
        int n = n0 + s2;
        int dgv = (k == 0) ? e0 : e1;
        if (n < N_NODES) rowoff[n] = ((obase + off[s2]) << 9) | min(dgv, 511);
    }
    for (int i = t; i < cnt; i += 256) {
        int p = ebuf[ibase + i];
        int nl = p & (NPB - 1);
        int o = atomicAdd(&cur[nl], 1);
        csr[obase + off[nl] + o] = p >> 9;
    }
}

// ---------------------------------------------------------------------------
// FUSED gather + self-GEMM (independent halves of the algebra, overlapped):
// every 17th block computes selfmm = h@Ws (bf16 -> lane-private 64B slots in
// row second-halves); other blocks run the proven 4-node/block bf16 gather,
// writing hn bf16 into row first-halves. Disjoint 128B cachelines.
// ---------------------------------------------------------------------------
template <bool BF>
__global__ __launch_bounds__(256) void gather_selfmm_kernel(
    const float* __restrict__ h, const unsigned short* __restrict__ hb,
    const int* __restrict__ rowoff, const int* __restrict__ csr,
    float* __restrict__ out, const unsigned short* __restrict__ wpack) {
    const int bid = blockIdx.x;
    const int t = threadIdx.x;
    if (bid % 17 == 0) {
        if (!BF) return;  // fp32 fallback: hn uses full rows; selfmm disabled
        // ---- self-GEMM: 64 nodes, wave = 16 nodes x 128 outs, Ws only ----
        const int sb = bid / 17;
        const int lane = t & 63;
        const int wid = t >> 6;
        const int node_base = sb * 64 + wid * 16;
        const int rowc = min(node_base + (lane & 15), N_NODES - 1);
        const int khi = lane >> 4;
        f32x4 acc[8] = {};
#pragma unroll
        for (int ks = 0; ks < 4; ++ks) {
            const int k0 = ks * 32 + khi * 8;
            bf16x8 ha = *reinterpret_cast<const bf16x8*>(hb + (size_t)rowc * DIM + k0);
#pragma unroll
            for (int nt = 0; nt < 8; ++nt) {
                bf16x8 bs = *reinterpret_cast<const bf16x8*>(
                    wpack + (size_t)(((nt * 4 + ks) * 64 + lane) * 8));
                acc[nt] = __builtin_amdgcn_mfma_f32_16x16x32_bf16(ha, bs, acc[nt], 0, 0, 0);
            }
        }
        // lane-private slot: row sb*64 + (t>>2), second half, (t&3)*32 ushorts in
        const int slotrow = sb * 64 + (t >> 2);
        if (slotrow < N_NODES) {
            unsigned short* base = reinterpret_cast<unsigned short*>(out) +
                                   (size_t)slotrow * 256 + 128 + (t & 3) * 32;
#pragma unroll
            for (int q = 0; q < 4; ++q) {
                u16x8 r;
#pragma unroll
                for (int j = 0; j < 8; ++j) {
                    const int pos = q * 8 + j;  // pos = nt*4 + rr
                    r[j] = f2bf(acc[pos >> 2][pos & 3]);
                }
                *reinterpret_cast<u16x8*>(base + q * 8) = r;
            }
        }
        return;
    }
    // ---- gather: 4 nodes/block, one wave per node, 4 slots x 16 lanes x 16B --
    const int gid = bid - bid / 17 - 1;
    if (gid >= GB) return;
    const int node = gid * 4 + (t >> 6);
    const int lane = t & 63;
    const int g = lane >> 4;   // edge slot
    const int c = lane & 15;   // 16B chunk within row
    const int pw = rowoff[node];
    const int lo = pw >> 9, dg = pw & 511, hi = lo + dg;
    float a0 = 0.f, a1 = 0.f, a2 = 0.f, a3 = 0.f;
    float a4 = 0.f, a5 = 0.f, a6 = 0.f, a7 = 0.f;
    if (BF) {
        int k = lo + g;
        for (; k + 4 < hi; k += 8) {  // 2 independent row loads in flight
            int s0 = csr[k], s1 = csr[k + 4];
            uint4 v = *reinterpret_cast<const uint4*>(hb + (size_t)s0 * DIM + c * 8);
            uint4 u = *reinterpret_cast<const uint4*>(hb + (size_t)s1 * DIM + c * 8);
            a0 += __uint_as_float(v.x << 16) + __uint_as_float(u.x << 16);
            a1 += __uint_as_float(v.x & 0xffff0000u) + __uint_as_float(u.x & 0xffff0000u);
            a2 += __uint_as_float(v.y << 16) + __uint_as_float(u.y << 16);
            a3 += __uint_as_float(v.y & 0xffff0000u) + __uint_as_float(u.y & 0xffff0000u);
            a4 += __uint_as_float(v.z << 16) + __uint_as_float(u.z << 16);
            a5 += __uint_as_float(v.z & 0xffff0000u) + __uint_as_float(u.z & 0xffff0000u);
            a6 += __uint_as_float(v.w << 16) + __uint_as_float(u.w << 16);
            a7 += __uint_as_float(v.w & 0xffff0000u) + __uint_as_float(u.w & 0xffff0000u);
        }
        if (k < hi) {
            uint4 v = *reinterpret_cast<const uint4*>(hb + (size_t)csr[k] * DIM + c * 8);
            a0 += __uint_as_float(v.x << 16);
            a1 += __uint_as_float(v.x & 0xffff0000u);
            a2 += __uint_as_float(v.y << 16);
            a3 += __uint_as_float(v.y & 0xffff0000u);
            a4 += __uint_as_float(v.z << 16);
            a5 += __uint_as_float(v.z & 0xffff0000u);
            a6 += __uint_as_float(v.w << 16);
            a7 += __uint_as_float(v.w & 0xffff0000u);
        }
    } else {
        for (int k = lo + g; k < hi; k += 4) {
            const float4* p = reinterpret_cast<const float4*>(h + (size_t)csr[k] * DIM + c * 8);
            float4 x = p[0], y = p[1];
            a0 += x.x; a1 += x.y; a2 += x.z; a3 += x.w;
            a4 += y.x; a5 += y.y; a6 += y.z; a7 += y.w;
        }
    }
    a0 += __shfl_xor(a0, 16, 64); a0 += __shfl_xor(a0, 32, 64);
    a1 += __shfl_xor(a1, 16, 64); a1 += __shfl_xor(a1, 32, 64);
    a2 += __shfl_xor(a2, 16, 64); a2 += __shfl_xor(a2, 32, 64);
    a3 += __shfl_xor(a3, 16, 64); a3 += __shfl_xor(a3, 32, 64);
    a4 += __shfl_xor(a4, 16, 64); a4 += __shfl_xor(a4, 32, 64);
    a5 += __shfl_xor(a5, 16, 64); a5 += __shfl_xor(a5, 32, 64);
    a6 += __shfl_xor(a6, 16, 64); a6 += __shfl_xor(a6, 32, 64);
    a7 += __shfl_xor(a7, 16, 64); a7 += __shfl_xor(a7, 32, 64);
    float inv = 1.0f / (float)max(dg, 1);
    if (g == 0) {
        if (BF) {
            u16x8 rr;
            rr[0] = f2bf(a0 * inv); rr[1] = f2bf(a1 * inv);
            rr[2] = f2bf(a2 * inv); rr[3] = f2bf(a3 * inv);
            rr[4] = f2bf(a4 * inv); rr[5] = f2bf(a5 * inv);
            rr[6] = f2bf(a6 * inv); rr[7] = f2bf(a7 * inv);
            *reinterpret_cast<u16x8*>(reinterpret_cast<unsigned short*>(out) +
                                      (size_t)node * 256 + c * 8) = rr;
        } else {
            float4 r0, r1;
            r0.x = a0 * inv; r0.y = a1 * inv; r0.z = a2 * inv; r0.w = a3 * inv;
            r1.x = a4 * inv; r1.y = a5 * inv; r1.z = a6 * inv; r1.w = a7 * inv;
            float4* q = reinterpret_cast<float4*>(out + (size_t)node * DIM + c * 8);
            q[0] = r0;
            q[1] = r1;
        }
    }
}

// ---------------------------------------------------------------------------
// FINAL: acc = self (bf16, lane-private slots) ; acc += hn@Wn ; out = acc+bavg.
// Self unpack precedes the MFMA loop -> vmcnt orders the in-place reads before
// the epilogue's overwrites (all row bytes are wave-owned).
// ---------------------------------------------------------------------------
template <bool BF>
__global__ __launch_bounds__(256) void final_gemm_kernel(
    const float* __restrict__ h, float* __restrict__ out,
    const unsigned short* __restrict__ wpack, const float* __restrict__ bavg) {
    const int lane = threadIdx.x & 63;
    const int wid = threadIdx.x >> 6;
    const int node_base = blockIdx.x * 64 + wid * 16;
    const int rowc = min(node_base + (lane & 15), N_NODES - 1);
    const int khi = lane >> 4;
    const unsigned short* us = reinterpret_cast<const unsigned short*>(out);
    f32x4 acc[8];
    if (BF) {
        const int slotrow = blockIdx.x * 64 + (threadIdx.x >> 2);
        if (slotrow < N_NODES) {
            const u16x8* base = reinterpret_cast<const u16x8*>(
                us + (size_t)slotrow * 256 + 128 + (threadIdx.x & 3) * 32);
#pragma unroll
            for (int q = 0; q < 4; ++q) {
                u16x8 r = base[q];
#pragma unroll
                for (int j = 0; j < 8; ++j) {
                    const int pos = q * 8 + j;  // nt = pos>>2, rr = pos&3
                    acc[pos >> 2][pos & 3] = __uint_as_float(((unsigned)(unsigned short)r[j]) << 16);
                }
            }
        } else {
#pragma unroll
            for (int nt = 0; nt < 8; ++nt) acc[nt] = (f32x4){0.f, 0.f, 0.f, 0.f};
        }
    } else {
#pragma unroll
        for (int nt = 0; nt < 8; ++nt) acc[nt] = (f32x4){0.f, 0.f, 0.f, 0.f};
    }
    const unsigned short* wn_p = wpack + 16384;
#pragma unroll
    for (int ks = 0; ks < 4; ++ks) {
        const int k0 = ks * 32 + khi * 8;
        bf16x8 na;
        if (BF) {
            na = *reinterpret_cast<const bf16x8*>(us + (size_t)rowc * 256 + k0);
        } else {
            const float4* np0 = reinterpret_cast<const float4*>(out + (size_t)rowc * DIM + k0);
            float4 u = np0[0], v = np0[1];
            na[0] = (short)f2bf(u.x); na[1] = (short)f2bf(u.y);
            na[2] = (short)f2bf(u.z); na[3] = (short)f2bf(u.w);
            na[4] = (short)f2bf(v.x); na[5] = (short)f2bf(v.y);
            na[6] = (short)f2bf(v.z); na[7] = (short)f2bf(v.w);
        }
#pragma unroll
        for (int nt = 0; nt < 8; ++nt) {
            bf16x8 bn = *reinterpret_cast<const bf16x8*>(
                wn_p + (size_t)(((nt * 4 + ks) * 64 + lane) * 8));
            acc[nt] = __builtin_amdgcn_mfma_f32_16x16x32_bf16(na, bn, acc[nt], 0, 0, 0);
        }
        if (!BF) {  // fp32 fallback also needs the self matmul here
            const float4* hp = reinterpret_cast<const float4*>(h + (size_t)rowc * DIM + k0);
            float4 x = hp[0], y = hp[1];
            bf16x8 ha;
            ha[0] = (short)f2bf(x.x); ha[1] = (short)f2bf(x.y);
            ha[2] = (short)f2bf(x.z); ha[3] = (short)f2bf(x.w);
            ha[4] = (short)f2bf(y.x); ha[5] = (short)f2bf(y.y);
            ha[6] = (short)f2bf(y.z); ha[7] = (short)f2bf(y.w);
#pragma unroll
            for (int nt = 0; nt < 8; ++nt) {
                bf16x8 bs = *reinterpret_cast<const bf16x8*>(
                    wpack + (size_t)(((nt * 4 + ks) * 64 + lane) * 8));
                acc[nt] = __builtin_amdgcn_mfma_f32_16x16x32_bf16(ha, bs, acc[nt], 0, 0, 0);
            }
        }
    }
    const int r0 = node_base + khi * 4;
#pragma unroll
    for (int nt = 0; nt < 8; ++nt) {
        int o = nt * 16 + (lane & 15);
        float bb = bavg[o];
#pragma unroll
        for (int r = 0; r < 4; ++r) {
            int nr = r0 + r;
            if (nr < N_NODES) out[(size_t)nr * DIM + o] = acc[nt][r] + bb;
        }
    }
}

extern "C" void kernel_launch(void* const* d_in, const int* in_sizes, int n_in,
                              void* d_out, int out_size, void* d_ws, size_t ws_size,
                              hipStream_t stream) {
    const float* h  = (const float*)d_in[0];
    const int* src  = (const int*)d_in[1];
    const int* dst  = (const int*)d_in[2];
    const float* Ws = (const float*)d_in[3];
    const float* Wn = (const float*)d_in[4];
    const float* b  = (const float*)d_in[5];
    float* out = (float*)d_out;

    char* ws = (char*)d_ws;
    int* bcur   = (int*)(ws + B_BCUR);
    int* rowoff = (int*)(ws + B_ROWOFF);
    int* csr    = (int*)(ws + B_CSR);
    unsigned short* wpack = (unsigned short*)(ws + B_WPACK);
    float* bavg = (float*)(ws + B_BAVG);
    unsigned short* hb = (unsigned short*)(ws + B_HB);
    int* ebuf   = (int*)d_out;  // padded buckets (12.6MB); dead before gather

    const bool bf = (ws_size >= NEED_BF16);

    hipMemsetAsync(bcur, 0, 256 * sizeof(int), stream);  // relative cursors

    if (bf)
        prep_scatter_kernel<true><<<NBLK + CVT_BLKS, 256, 0, stream>>>(
            src, dst, bcur, ebuf, h, hb, Ws, Wn, b, wpack, bavg);
    else
        prep_scatter_kernel<false><<<NBLK + CVT_BLKS, 256, 0, stream>>>(
            src, dst, bcur, ebuf, h, hb, Ws, Wn, b, wpack, bavg);
    csr_build_kernel<<<NB, 256, 0, stream>>>(bcur, ebuf, rowoff, csr);
    if (bf) {
        gather_selfmm_kernel<true><<<FUSED_GRID, 256, 0, stream>>>(
            h, hb, rowoff, csr, out, wpack);
        final_gemm_kernel<true><<<SMB, 256, 0, stream>>>(h, out, wpack, bavg);
    } else {
        gather_selfmm_kernel<false><<<FUSED_GRID, 256, 0, stream>>>(
            h, hb, rowoff, csr, out, wpack);
        final_gemm_kernel<false><<<SMB, 256, 0, stream>>>(h, out, wpack, bavg);
    }
}

// Round 14
// 146.436 us; speedup vs baseline: 1.2179x; 1.2179x over previous
//
#include <hip/hip_runtime.h>

#define N_NODES 100000
#define N_EDGES 1600000
#define DIM 128
#define NH 4

#define NPB 512                                   // nodes per coarse bucket
#define NB 196                                    // buckets
#define CAP 12288                                 // padded bucket capacity (mean 8192)
#define BCHUNK 8192                               // edges per scatter block
#define BEPT 32                                   // BCHUNK / 256
#define NBLK 196                                  // scatter blocks
#define NCHUNK (N_NODES * DIM / 8)                // 1.6M 8-elem conversion chunks
#define CVT_BLKS (NCHUNK / 256)                   // 6250 prep blocks, 1 chunk/thread

typedef __attribute__((ext_vector_type(8))) short bf16x8;
typedef __attribute__((ext_vector_type(4))) float f32x4;
typedef __attribute__((ext_vector_type(2))) float f32x2;
typedef __attribute__((ext_vector_type(8))) unsigned short u16x8;

// ws layout, BYTE offsets:
//   bcur   : [0, 1024)           int[256] RELATIVE bucket cursors (memset 0)
//   rowoff : [4096, 404096)      int[100000] packed (csr_lo<<9)|deg
//   csr    : [405504, 6805504)   int[1.6M] src ids, dense, bucketed+sorted by dst
//   wpack  : [6805504, 6871040)  bf16 MFMA-packed Ws|Wn
//   bavg   : [6871040, 6871552)  f32[128]
//   h8     : [6871552, 19671552) fp8 e4m3 copy of h (12.8MB), neighbor path
// ebuf (padded buckets, 256*CAP ints = 12.6MB) lives in d_out: dead before gather.
#define B_BCUR   0u
#define B_ROWOFF 4096u
#define B_CSR    405504u
#define B_WPACK  6805504u
#define B_BAVG   6871040u
#define B_H8     6871552u
#define NEED_BF16 32869376ull

// branchless RTNE f32->bf16 (finite inputs; no NaN path)
__device__ inline unsigned short f2bf(float x) {
    union { float f; unsigned u; } v; v.f = x;
    unsigned r = v.u + 0x7fffu + ((v.u >> 16) & 1u);
    return (unsigned short)(r >> 16);
}

// decode 16 fp8 e4m3 (uint4) -> accumulate into 16 f32 (HW cvt)
__device__ inline void acc_fp8(float (&a)[16], uint4 v) {
    f32x2 r;
    r = __builtin_amdgcn_cvt_pk_f32_fp8((int)v.x, false); a[0] += r[0]; a[1] += r[1];
    r = __builtin_amdgcn_cvt_pk_f32_fp8((int)v.x, true);  a[2] += r[0]; a[3] += r[1];
    r = __builtin_amdgcn_cvt_pk_f32_fp8((int)v.y, false); a[4] += r[0]; a[5] += r[1];
    r = __builtin_amdgcn_cvt_pk_f32_fp8((int)v.y, true);  a[6] += r[0]; a[7] += r[1];
    r = __builtin_amdgcn_cvt_pk_f32_fp8((int)v.z, false); a[8] += r[0]; a[9] += r[1];
    r = __builtin_amdgcn_cvt_pk_f32_fp8((int)v.z, true);  a[10] += r[0]; a[11] += r[1];
    r = __builtin_amdgcn_cvt_pk_f32_fp8((int)v.w, false); a[12] += r[0]; a[13] += r[1];
    r = __builtin_amdgcn_cvt_pk_f32_fp8((int)v.w, true);  a[14] += r[0]; a[15] += r[1];
}

__device__ inline void acc_f32(float (&a)[16], const float4* p) {
    float4 x0 = p[0], x1 = p[1], x2 = p[2], x3 = p[3];
    a[0] += x0.x; a[1] += x0.y; a[2] += x0.z; a[3] += x0.w;
    a[4] += x1.x; a[5] += x1.y; a[6] += x1.z; a[7] += x1.w;
    a[8] += x2.x; a[9] += x2.y; a[10] += x2.z; a[11] += x2.w;
    a[12] += x3.x; a[13] += x3.y; a[14] += x3.z; a[15] += x3.w;
}

// ---------------------------------------------------------------------------
// MERGED scatter + prep. Blocks [0,NBLK): single-pass bucket scatter into the
// padded ebuf (relative cursors; ~32-edge cacheline runs). Blocks [NBLK, ...):
// FULLY PARALLEL prep — 1 chunk/thread fp8 conversion (6250 blocks, same shape
// as R10's standalone prep), weight pack (first 64 prep blocks), bavg (block 0).
// Scatter holds <=196 CUs; prep streams on the remaining 60+ and finishes with
// the scatter instead of serially after it.
// ---------------------------------------------------------------------------
template <bool F8>
__global__ __launch_bounds__(256) void scatter_prep_kernel(
    const int* __restrict__ src, const int* __restrict__ dst,
    int* __restrict__ bcur, int* __restrict__ ebuf,
    const float* __restrict__ h, unsigned char* __restrict__ h8,
    const float* __restrict__ Ws, const float* __restrict__ Wn,
    const float* __restrict__ b, unsigned short* __restrict__ wpack,
    float* __restrict__ bavg) {
    const int t = threadIdx.x;
    if (blockIdx.x >= NBLK) {
        // ---- prep path ----
        const int pb = blockIdx.x - NBLK;
        const int i = pb * 256 + t;
        if (i < DIM * DIM) {
            float s = 0.f, n = 0.f;
#pragma unroll
            for (int hh = 0; hh < NH; ++hh) {
                s += Ws[hh * DIM * DIM + i];
                n += Wn[hh * DIM * DIM + i];
            }
            s *= 0.25f; n *= 0.25f;
            int k = i >> 7, o = i & 127;
            int nt = o >> 4, lanelo = o & 15;
            int ks = k >> 5, lanehi = (k & 31) >> 3, e = k & 7;
            int pos = (((nt * 4 + ks) * 64) + lanehi * 16 + lanelo) * 8 + e;
            wpack[pos] = f2bf(s);
            wpack[16384 + pos] = f2bf(n);
        }
        if (i < DIM) {
            float bb = 0.f;
#pragma unroll
            for (int hh = 0; hh < NH; ++hh) bb += b[hh * DIM + i];
            bavg[i] = 0.25f * bb;
        }
        if (F8 && i < NCHUNK) {  // 8 elems/thread fp8 conversion (RTNE in HW)
            const float4* p = reinterpret_cast<const float4*>(h) + (size_t)i * 2;
            float4 a = p[0], c = p[1];
            int d0 = 0, d1 = 0;
            d0 = __builtin_amdgcn_cvt_pk_fp8_f32(a.x, a.y, d0, false);
            d0 = __builtin_amdgcn_cvt_pk_fp8_f32(a.z, a.w, d0, true);
            d1 = __builtin_amdgcn_cvt_pk_fp8_f32(c.x, c.y, d1, false);
            d1 = __builtin_amdgcn_cvt_pk_fp8_f32(c.z, c.w, d1, true);
            reinterpret_cast<uint2*>(h8)[i] = make_uint2((unsigned)d0, (unsigned)d1);
        }
        return;
    }
    // ---- scatter path ----
    __shared__ int stage[BCHUNK];
    __shared__ unsigned char bkt[BCHUNK];
    __shared__ int lc[256], lbase[256], lpos[256];
    lc[t] = 0;
    lpos[t] = 0;
    __syncthreads();
    int e0 = blockIdx.x * BCHUNK;
#pragma unroll 4
    for (int j = 0; j < BEPT; ++j) {
        int e = e0 + j * 256 + t;
        if (e < N_EDGES) {
            int d = dst[e];
            stage[j * 256 + t] = (src[e] << 9) | (d & (NPB - 1));
            bkt[j * 256 + t] = (unsigned char)(d >> 9);
            atomicAdd(&lc[d >> 9], 1);
        }
    }
    __syncthreads();
    if (lc[t]) lbase[t] = t * CAP + atomicAdd(&bcur[t], lc[t]);  // relative cursors
    __syncthreads();
#pragma unroll 4
    for (int j = 0; j < BEPT; ++j) {
        int e = e0 + j * 256 + t;
        if (e < N_EDGES) {
            int bb = bkt[j * 256 + t];
            int o = atomicAdd(&lpos[bb], 1);
            ebuf[lbase[bb] + o] = stage[j * 256 + t];
        }
    }
}

// ---------------------------------------------------------------------------
// one block per bucket: internal 256-bucket scan, local 512-slot hist + scan
// -> packed rowoff ((lo<<9)|deg), then scatter src into the dense csr window.
// ---------------------------------------------------------------------------
__global__ __launch_bounds__(256) void csr_build_kernel(const int* __restrict__ bcur,
                                                        const int* __restrict__ ebuf,
                                                        int* __restrict__ rowoff,
                                                        int* __restrict__ csr) {
    __shared__ int hh[NPB], off[NPB], cur[NPB], ss[256];
    int b = blockIdx.x, t = threadIdx.x;
    int cnt = bcur[b];           // relative count
    int ibase = b * CAP;
    ss[t] = bcur[t];
    __syncthreads();
    for (int o = 1; o < 256; o <<= 1) {
        int add = (t >= o) ? ss[t - o] : 0;
        __syncthreads();
        ss[t] += add;
        __syncthreads();
    }
    int obase = ss[b] - cnt;
    hh[t] = 0; hh[t + 256] = 0;
    cur[t] = 0; cur[t + 256] = 0;
    __syncthreads();
    for (int i = t; i < cnt; i += 256) atomicAdd(&hh[ebuf[ibase + i] & (NPB - 1)], 1);
    __syncthreads();
    int e0 = hh[2 * t], e1 = hh[2 * t + 1];
    ss[t] = e0 + e1;
    __syncthreads();
    for (int o = 1; o < 256; o <<= 1) {
        int add = (t >= o) ? ss[t - o] : 0;
        __syncthreads();
        ss[t] += add;
        __syncthreads();
    }
    int ex = ss[t] - (e0 + e1);
    off[2 * t] = ex;
    off[2 * t + 1] = ex + e0;
    __syncthreads();
    int n0 = b * NPB;
#pragma unroll
    for (int k = 0; k < 2; ++k) {
        int s2 = 2 * t + k;
        int n = n0 + s2;
        int dgv = (k == 0) ? e0 : e1;
        if (n < N_NODES) rowoff[n] = ((obase + off[s2]) << 9) | min(dgv, 511);
    }
    for (int i = t; i < cnt; i += 256) {
        int p = ebuf[ibase + i];
        int nl = p & (NPB - 1);
        int o = atomicAdd(&cur[nl], 1);
        csr[obase + off[nl] + o] = p >> 9;
    }
}

// ---------------------------------------------------------------------------
// gather-mean (R10's proven config, UNMODIFIED): 25000 blocks, one wave per
// node; 8 edge-slots x 8 lanes x 16B, 2-deep ILP. fp8 rows via HW cvt; deg<8
// nodes take the fp32-row fallback. Mean row written as packed bf16 into the
// FIRST HALF of the node's out row. Keep this kernel LEAN: no co-compiled
// heavy paths (R13 lesson: union-VGPR kills the latency-bound gather).
// ---------------------------------------------------------------------------
template <bool F8>
__global__ __launch_bounds__(256) void gather_mean_kernel(
    const float* __restrict__ h, const unsigned char* __restrict__ h8,
    const int* __restrict__ rowoff, const int* __restrict__ csr,
    float* __restrict__ out) {
    const int node = blockIdx.x * 4 + (threadIdx.x >> 6);
    const int lane = threadIdx.x & 63;
    const int s = lane >> 3;   // edge slot 0..7
    const int c = lane & 7;    // 16-elem chunk 0..7
    const int w = rowoff[node];
    const int lo = w >> 9, dg = w & 511, hi = lo + dg;
    float a[16];
#pragma unroll
    for (int i = 0; i < 16; ++i) a[i] = 0.f;
    if (F8 && dg >= 8) {
        int k = lo + s;
        for (; k + 8 < hi; k += 16) {  // 2 independent row loads in flight
            int s0 = csr[k], s1 = csr[k + 8];
            uint4 v = *reinterpret_cast<const uint4*>(h8 + (size_t)s0 * DIM + c * 16);
            uint4 u = *reinterpret_cast<const uint4*>(h8 + (size_t)s1 * DIM + c * 16);
            acc_fp8(a, v);
            acc_fp8(a, u);
        }
        for (; k < hi; k += 8) {
            uint4 v = *reinterpret_cast<const uint4*>(h8 + (size_t)csr[k] * DIM + c * 16);
            acc_fp8(a, v);
        }
    } else {
        for (int k = lo + s; k < hi; k += 8)
            acc_f32(a, reinterpret_cast<const float4*>(h + (size_t)csr[k] * DIM + c * 16));
    }
#pragma unroll
    for (int i = 0; i < 16; ++i) {
        a[i] += __shfl_xor(a[i], 8, 64);
        a[i] += __shfl_xor(a[i], 16, 64);
        a[i] += __shfl_xor(a[i], 32, 64);
    }
    float inv = 1.0f / (float)max(dg, 1);
    if (s == 0) {
        if (F8) {
            u16x8 r0, r1;
#pragma unroll
            for (int j = 0; j < 8; ++j) {
                r0[j] = f2bf(a[j] * inv);
                r1[j] = f2bf(a[8 + j] * inv);
            }
            unsigned short* base = reinterpret_cast<unsigned short*>(out) + (size_t)node * 256 + c * 16;
            *reinterpret_cast<u16x8*>(base) = r0;
            *reinterpret_cast<u16x8*>(base + 8) = r1;
        } else {
            float4* q = reinterpret_cast<float4*>(out + (size_t)node * DIM + c * 16);
            q[0] = make_float4(a[0] * inv, a[1] * inv, a[2] * inv, a[3] * inv);
            q[1] = make_float4(a[4] * inv, a[5] * inv, a[6] * inv, a[7] * inv);
            q[2] = make_float4(a[8] * inv, a[9] * inv, a[10] * inv, a[11] * inv);
            q[3] = make_float4(a[12] * inv, a[13] * inv, a[14] * inv, a[15] * inv);
        }
    }
}

// ---------------------------------------------------------------------------
// MFMA GEMM (R10 exact): out[n] = h[n]@Ws + hn[n]@Wn + bavg. Self path reads
// h fp32 + f2bf; hn is packed bf16 in the first half of each out row
// (wave-local in-place overwrite). Wave = 16 nodes x 128 outs, 4 k-steps.
// ---------------------------------------------------------------------------
template <bool F8>
__global__ __launch_bounds__(256) void mfma_gemm_kernel(
    const float* __restrict__ h, float* __restrict__ out,
    const unsigned short* __restrict__ wpack, const float* __restrict__ bavg) {
    const int lane = threadIdx.x & 63;
    const int wid = threadIdx.x >> 6;
    const int node_base = blockIdx.x * 64 + wid * 16;
    const int row = node_base + (lane & 15);
    const int rowc = min(row, N_NODES - 1);
    const int khi = lane >> 4;

    f32x4 acc[8] = {};
    const unsigned short* wn_p = wpack + 16384;

#pragma unroll
    for (int ks = 0; ks < 4; ++ks) {
        const int k0 = ks * 32 + khi * 8;
        bf16x8 ha, na;
        const float4* hp = reinterpret_cast<const float4*>(h + (size_t)rowc * DIM + k0);
        float4 x = hp[0], y = hp[1];
        ha[0] = (short)f2bf(x.x); ha[1] = (short)f2bf(x.y);
        ha[2] = (short)f2bf(x.z); ha[3] = (short)f2bf(x.w);
        ha[4] = (short)f2bf(y.x); ha[5] = (short)f2bf(y.y);
        ha[6] = (short)f2bf(y.z); ha[7] = (short)f2bf(y.w);
        if (F8) {
            na = *reinterpret_cast<const bf16x8*>(
                reinterpret_cast<const unsigned short*>(out) + (size_t)rowc * 256 + k0);
        } else {
            const float4* np0 = reinterpret_cast<const float4*>(out + (size_t)rowc * DIM + k0);
            float4 u = np0[0], v = np0[1];
            na[0] = (short)f2bf(u.x); na[1] = (short)f2bf(u.y);
            na[2] = (short)f2bf(u.z); na[3] = (short)f2bf(u.w);
            na[4] = (short)f2bf(v.x); na[5] = (short)f2bf(v.y);
            na[6] = (short)f2bf(v.z); na[7] = (short)f2bf(v.w);
        }

#pragma unroll
        for (int nt = 0; nt < 8; ++nt) {
            bf16x8 bs = *reinterpret_cast<const bf16x8*>(wpack + (size_t)(((nt * 4 + ks) * 64 + lane) * 8));
            acc[nt] = __builtin_amdgcn_mfma_f32_16x16x32_bf16(ha, bs, acc[nt], 0, 0, 0);
            bf16x8 bn = *reinterpret_cast<const bf16x8*>(wn_p + (size_t)(((nt * 4 + ks) * 64 + lane) * 8));
            acc[nt] = __builtin_amdgcn_mfma_f32_16x16x32_bf16(na, bn, acc[nt], 0, 0, 0);
        }
    }

    // C/D layout (verified m89): col = lane&15, row = (lane>>4)*4 + reg
    const int r0 = node_base + khi * 4;
#pragma unroll
    for (int nt = 0; nt < 8; ++nt) {
        int o = nt * 16 + (lane & 15);
        float bb = bavg[o];
#pragma unroll
        for (int r = 0; r < 4; ++r) {
            int nr = r0 + r;
            if (nr < N_NODES) out[(size_t)nr * DIM + o] = acc[nt][r] + bb;
        }
    }
}

extern "C" void kernel_launch(void* const* d_in, const int* in_sizes, int n_in,
                              void* d_out, int out_size, void* d_ws, size_t ws_size,
                              hipStream_t stream) {
    const float* h  = (const float*)d_in[0];
    const int* src  = (const int*)d_in[1];
    const int* dst  = (const int*)d_in[2];
    const float* Ws = (const float*)d_in[3];
    const float* Wn = (const float*)d_in[4];
    const float* b  = (const float*)d_in[5];
    float* out = (float*)d_out;

    char* ws = (char*)d_ws;
    int* bcur   = (int*)(ws + B_BCUR);
    int* rowoff = (int*)(ws + B_ROWOFF);
    int* csr    = (int*)(ws + B_CSR);
    unsigned short* wpack = (unsigned short*)(ws + B_WPACK);
    float* bavg = (float*)(ws + B_BAVG);
    unsigned char* h8 = (unsigned char*)(ws + B_H8);
    int* ebuf   = (int*)d_out;  // padded buckets (12.6MB); dead before gather

    const bool f8 = (ws_size >= NEED_BF16);

    hipMemsetAsync(bcur, 0, 256 * sizeof(int), stream);  // relative cursors

    if (f8)
        scatter_prep_kernel<true><<<NBLK + CVT_BLKS, 256, 0, stream>>>(
            src, dst, bcur, ebuf, h, h8, Ws, Wn, b, wpack, bavg);
    else
        scatter_prep_kernel<false><<<NBLK + 64, 256, 0, stream>>>(
            src, dst, bcur, ebuf, h, h8, Ws, Wn, b, wpack, bavg);
    csr_build_kernel<<<NB, 256, 0, stream>>>(bcur, ebuf, rowoff, csr);
    if (f8)
        gather_mean_kernel<true><<<N_NODES / 4, 256, 0, stream>>>(h, h8, rowoff, csr, out);
    else
        gather_mean_kernel<false><<<N_NODES / 4, 256, 0, stream>>>(h, h8, rowoff, csr, out);
    const int gemm_blocks = (N_NODES + 63) / 64;
    if (f8)
        mfma_gemm_kernel<true><<<gemm_blocks, 256, 0, stream>>>(h, out, wpack, bavg);
    else
        mfma_gemm_kernel<false><<<gemm_blocks, 256, 0, stream>>>(h, out, wpack, bavg);
}

// Round 15
// 139.144 us; speedup vs baseline: 1.2817x; 1.0524x over previous
//
#include <hip/hip_runtime.h>

#define N_NODES 100000
#define N_EDGES 1600000
#define DIM 128
#define NH 4

#define NPB 512                                   // nodes per coarse bucket
#define NB 196                                    // buckets
#define CAP 12288                                 // padded bucket capacity (mean 8192)
#define BCHUNK 8192                               // edges per scatter block
#define SPT 512                                   // scatter/prep/csr threads per block
#define BEPT (BCHUNK / SPT)                       // 16
#define NBLK 196                                  // scatter blocks
#define NCHUNK (N_NODES * DIM / 8)                // 1.6M 8-elem conversion chunks
#define CVT_BLKS (NCHUNK / SPT)                   // 3125 prep blocks, 1 chunk/thread

typedef __attribute__((ext_vector_type(8))) short bf16x8;
typedef __attribute__((ext_vector_type(4))) float f32x4;
typedef __attribute__((ext_vector_type(8))) unsigned short u16x8;

// ws layout, BYTE offsets:
//   bcur   : [0, 1024)           int[256] RELATIVE bucket cursors (memset 0)
//   rowoff : [4096, 404096)      int[100000] packed (csr_lo<<9)|deg
//   csr    : [405504, 6805504)   int[1.6M] src ids, dense, bucketed+sorted by dst
//   wpack  : [6805504, 6871040)  bf16 MFMA-packed Ws|Wn
//   bavg   : [6871040, 6871552)  f32[128]
//   hb     : [6871552, 32471552) bf16 copy of h (25.6MB)
// ebuf (padded buckets, 256*CAP ints = 12.6MB) lives in d_out: dead before gather.
#define B_BCUR   0u
#define B_ROWOFF 4096u
#define B_CSR    405504u
#define B_WPACK  6805504u
#define B_BAVG   6871040u
#define B_HB     6871552u
#define NEED_BF16 32869376ull

// branchless RTNE f32->bf16 (finite inputs; no NaN path)
__device__ inline unsigned short f2bf(float x) {
    union { float f; unsigned u; } v; v.f = x;
    unsigned r = v.u + 0x7fffu + ((v.u >> 16) & 1u);
    return (unsigned short)(r >> 16);
}

// ---------------------------------------------------------------------------
// MERGED scatter + prep, 512 threads. Blocks [0,NBLK): single-pass bucket
// scatter (relative cursors, ~32-edge cacheline runs, 2x issue width vs R14).
// Blocks [NBLK,...): fully parallel prep — 1 chunk/thread h->bf16 conversion,
// weight pack (first 32 prep blocks), bavg (block 0 of prep range).
// ---------------------------------------------------------------------------
template <bool BF>
__global__ __launch_bounds__(SPT) void scatter_prep_kernel(
    const int* __restrict__ src, const int* __restrict__ dst,
    int* __restrict__ bcur, int* __restrict__ ebuf,
    const float* __restrict__ h, unsigned short* __restrict__ hb,
    const float* __restrict__ Ws, const float* __restrict__ Wn,
    const float* __restrict__ b, unsigned short* __restrict__ wpack,
    float* __restrict__ bavg) {
    const int t = threadIdx.x;
    if (blockIdx.x >= NBLK) {
        // ---- prep path ----
        const int pb = blockIdx.x - NBLK;
        const int i = pb * SPT + t;
        if (i < DIM * DIM) {
            float s = 0.f, n = 0.f;
#pragma unroll
        for (int hh = 0; hh < NH; ++hh) {
                s += Ws[hh * DIM * DIM + i];
                n += Wn[hh * DIM * DIM + i];
            }
            s *= 0.25f; n *= 0.25f;
            int k = i >> 7, o = i & 127;
            int nt = o >> 4, lanelo = o & 15;
            int ks = k >> 5, lanehi = (k & 31) >> 3, e = k & 7;
            int pos = (((nt * 4 + ks) * 64) + lanehi * 16 + lanelo) * 8 + e;
            wpack[pos] = f2bf(s);
            wpack[16384 + pos] = f2bf(n);
        }
        if (i < DIM) {
            float bb = 0.f;
#pragma unroll
            for (int hh = 0; hh < NH; ++hh) bb += b[hh * DIM + i];
            bavg[i] = 0.25f * bb;
        }
        if (BF && i < NCHUNK) {  // 8 elems/thread bf16 conversion
            const float4* p = reinterpret_cast<const float4*>(h) + (size_t)i * 2;
            float4 a = p[0], c = p[1];
            u16x8 r;
            r[0] = f2bf(a.x); r[1] = f2bf(a.y); r[2] = f2bf(a.z); r[3] = f2bf(a.w);
            r[4] = f2bf(c.x); r[5] = f2bf(c.y); r[6] = f2bf(c.z); r[7] = f2bf(c.w);
            reinterpret_cast<u16x8*>(hb)[i] = r;
        }
        return;
    }
    // ---- scatter path (512 threads) ----
    __shared__ int stage[BCHUNK];
    __shared__ unsigned char bkt[BCHUNK];
    __shared__ int lc[256], lbase[256], lpos[256];
    if (t < 256) { lc[t] = 0; lpos[t] = 0; }
    __syncthreads();
    int e0 = blockIdx.x * BCHUNK;
#pragma unroll 4
    for (int j = 0; j < BEPT; ++j) {
        int e = e0 + j * SPT + t;
        if (e < N_EDGES) {
            int d = dst[e];
            stage[j * SPT + t] = (src[e] << 9) | (d & (NPB - 1));
            bkt[j * SPT + t] = (unsigned char)(d >> 9);
            atomicAdd(&lc[d >> 9], 1);
        }
    }
    __syncthreads();
    if (t < 256 && lc[t]) lbase[t] = t * CAP + atomicAdd(&bcur[t], lc[t]);
    __syncthreads();
#pragma unroll 4
    for (int j = 0; j < BEPT; ++j) {
        int e = e0 + j * SPT + t;
        if (e < N_EDGES) {
            int bb = bkt[j * SPT + t];
            int o = atomicAdd(&lpos[bb], 1);
            ebuf[lbase[bb] + o] = stage[j * SPT + t];
        }
    }
}

// ---------------------------------------------------------------------------
// one block per bucket, 512 threads: internal 256-bucket scan, 512-slot hist
// (1 slot/thread) + 512-wide scan -> packed rowoff ((lo<<9)|deg), then scatter
// src into the dense csr window (L2-resident).
// ---------------------------------------------------------------------------
__global__ __launch_bounds__(SPT) void csr_build_kernel(const int* __restrict__ bcur,
                                                        const int* __restrict__ ebuf,
                                                        int* __restrict__ rowoff,
                                                        int* __restrict__ csr) {
    __shared__ int sh[256];
    __shared__ int hh[NPB], off[NPB], cur[NPB], ss2[NPB];
    const int b = blockIdx.x, t = threadIdx.x;
    const int cnt = bcur[b];     // relative count
    const int ibase = b * CAP;
    // exclusive scan of 256 bucket counts (t<256 active; barriers block-wide)
    if (t < 256) sh[t] = bcur[t];
    __syncthreads();
    for (int o = 1; o < 256; o <<= 1) {
        int add = (t < 256 && t >= o) ? sh[t - o] : 0;
        __syncthreads();
        if (t < 256) sh[t] += add;
        __syncthreads();
    }
    const int obase = sh[b] - cnt;
    hh[t] = 0;
    cur[t] = 0;
    __syncthreads();
    for (int i = t; i < cnt; i += SPT) atomicAdd(&hh[ebuf[ibase + i] & (NPB - 1)], 1);
    __syncthreads();
    const int myc = hh[t];
    ss2[t] = myc;
    __syncthreads();
    for (int o = 1; o < NPB; o <<= 1) {
        int add = (t >= o) ? ss2[t - o] : 0;
        __syncthreads();
        ss2[t] += add;
        __syncthreads();
    }
    off[t] = ss2[t] - myc;
    __syncthreads();
    const int n = b * NPB + t;
    if (n < N_NODES) rowoff[n] = ((obase + off[t]) << 9) | min(myc, 511);
    for (int i = t; i < cnt; i += SPT) {
        int p = ebuf[ibase + i];
        int nl = p & (NPB - 1);
        int o = atomicAdd(&cur[nl], 1);
        csr[obase + off[nl] + o] = p >> 9;
    }
}

// ---------------------------------------------------------------------------
// gather-mean (R9's proven bf16 config, UNMODIFIED): 25000 blocks, one wave
// per node; 4 edge-slots x 16 lanes x 16B, 2-deep ILP. Mean row written as
// packed bf16 into the FIRST HALF of the node's out row. Keep LEAN — no
// co-compiled heavy paths (R13 lesson).
// ---------------------------------------------------------------------------
template <bool BF>
__global__ __launch_bounds__(256) void gather_mean_kernel(
    const float* __restrict__ h, const unsigned short* __restrict__ hb,
    const int* __restrict__ rowoff, const int* __restrict__ csr,
    float* __restrict__ out) {
    const int node = blockIdx.x * 4 + (threadIdx.x >> 6);
    const int lane = threadIdx.x & 63;
    const int g = lane >> 4;   // edge slot
    const int c = lane & 15;   // 16B chunk within row
    const int w = rowoff[node];
    const int lo = w >> 9, dg = w & 511, hi = lo + dg;
    float a0 = 0.f, a1 = 0.f, a2 = 0.f, a3 = 0.f;
    float a4 = 0.f, a5 = 0.f, a6 = 0.f, a7 = 0.f;
    if (BF) {
        int k = lo + g;
        for (; k + 4 < hi; k += 8) {  // 2 independent row loads in flight
            int s0 = csr[k], s1 = csr[k + 4];
            uint4 v = *reinterpret_cast<const uint4*>(hb + (size_t)s0 * DIM + c * 8);
            uint4 u = *reinterpret_cast<const uint4*>(hb + (size_t)s1 * DIM + c * 8);
            a0 += __uint_as_float(v.x << 16) + __uint_as_float(u.x << 16);
            a1 += __uint_as_float(v.x & 0xffff0000u) + __uint_as_float(u.x & 0xffff0000u);
            a2 += __uint_as_float(v.y << 16) + __uint_as_float(u.y << 16);
            a3 += __uint_as_float(v.y & 0xffff0000u) + __uint_as_float(u.y & 0xffff0000u);
            a4 += __uint_as_float(v.z << 16) + __uint_as_float(u.z << 16);
            a5 += __uint_as_float(v.z & 0xffff0000u) + __uint_as_float(u.z & 0xffff0000u);
            a6 += __uint_as_float(v.w << 16) + __uint_as_float(u.w << 16);
            a7 += __uint_as_float(v.w & 0xffff0000u) + __uint_as_float(u.w & 0xffff0000u);
        }
        if (k < hi) {
            uint4 v = *reinterpret_cast<const uint4*>(hb + (size_t)csr[k] * DIM + c * 8);
            a0 += __uint_as_float(v.x << 16);
            a1 += __uint_as_float(v.x & 0xffff0000u);
            a2 += __uint_as_float(v.y << 16);
            a3 += __uint_as_float(v.y & 0xffff0000u);
            a4 += __uint_as_float(v.z << 16);
            a5 += __uint_as_float(v.z & 0xffff0000u);
            a6 += __uint_as_float(v.w << 16);
            a7 += __uint_as_float(v.w & 0xffff0000u);
        }
    } else {
        for (int k = lo + g; k < hi; k += 4) {
            const float4* p = reinterpret_cast<const float4*>(h + (size_t)csr[k] * DIM + c * 8);
            float4 x = p[0], y = p[1];
            a0 += x.x; a1 += x.y; a2 += x.z; a3 += x.w;
            a4 += y.x; a5 += y.y; a6 += y.z; a7 += y.w;
        }
    }
    a0 += __shfl_xor(a0, 16, 64); a0 += __shfl_xor(a0, 32, 64);
    a1 += __shfl_xor(a1, 16, 64); a1 += __shfl_xor(a1, 32, 64);
    a2 += __shfl_xor(a2, 16, 64); a2 += __shfl_xor(a2, 32, 64);
    a3 += __shfl_xor(a3, 16, 64); a3 += __shfl_xor(a3, 32, 64);
    a4 += __shfl_xor(a4, 16, 64); a4 += __shfl_xor(a4, 32, 64);
    a5 += __shfl_xor(a5, 16, 64); a5 += __shfl_xor(a5, 32, 64);
    a6 += __shfl_xor(a6, 16, 64); a6 += __shfl_xor(a6, 32, 64);
    a7 += __shfl_xor(a7, 16, 64); a7 += __shfl_xor(a7, 32, 64);
    float inv = 1.0f / (float)max(dg, 1);
    if (g == 0) {
        if (BF) {
            u16x8 rr;
            rr[0] = f2bf(a0 * inv); rr[1] = f2bf(a1 * inv);
            rr[2] = f2bf(a2 * inv); rr[3] = f2bf(a3 * inv);
            rr[4] = f2bf(a4 * inv); rr[5] = f2bf(a5 * inv);
            rr[6] = f2bf(a6 * inv); rr[7] = f2bf(a7 * inv);
            *reinterpret_cast<u16x8*>(reinterpret_cast<unsigned short*>(out) +
                                      (size_t)node * 256 + c * 8) = rr;
        } else {
            float4 r0, r1;
            r0.x = a0 * inv; r0.y = a1 * inv; r0.z = a2 * inv; r0.w = a3 * inv;
            r1.x = a4 * inv; r1.y = a5 * inv; r1.z = a6 * inv; r1.w = a7 * inv;
            float4* q = reinterpret_cast<float4*>(out + (size_t)node * DIM + c * 8);
            q[0] = r0;
            q[1] = r1;
        }
    }
}

// ---------------------------------------------------------------------------
// MFMA GEMM (R9 exact): out[n] = h[n]@Ws + hn[n]@Wn + bavg. BF path: ha from
// the bf16 hb copy (halves self-read traffic, no f2bf); hn is packed bf16 in
// the first half of each out row (wave-local in-place overwrite).
// ---------------------------------------------------------------------------
template <bool BF>
__global__ __launch_bounds__(256) void mfma_gemm_kernel(
    const float* __restrict__ h, const unsigned short* __restrict__ hb,
    float* __restrict__ out, const unsigned short* __restrict__ wpack,
    const float* __restrict__ bavg) {
    const int lane = threadIdx.x & 63;
    const int wid = threadIdx.x >> 6;
    const int node_base = blockIdx.x * 64 + wid * 16;
    const int rowc = min(node_base + (lane & 15), N_NODES - 1);
    const int khi = lane >> 4;

    f32x4 acc[8] = {};
    const unsigned short* wn_p = wpack + 16384;

#pragma unroll
    for (int ks = 0; ks < 4; ++ks) {
        const int k0 = ks * 32 + khi * 8;
        bf16x8 ha, na;
        if (BF) {
            ha = *reinterpret_cast<const bf16x8*>(hb + (size_t)rowc * DIM + k0);
            na = *reinterpret_cast<const bf16x8*>(
                reinterpret_cast<const unsigned short*>(out) + (size_t)rowc * 256 + k0);
        } else {
            const float4* hp = reinterpret_cast<const float4*>(h + (size_t)rowc * DIM + k0);
            float4 x = hp[0], y = hp[1];
            ha[0] = (short)f2bf(x.x); ha[1] = (short)f2bf(x.y);
            ha[2] = (short)f2bf(x.z); ha[3] = (short)f2bf(x.w);
            ha[4] = (short)f2bf(y.x); ha[5] = (short)f2bf(y.y);
            ha[6] = (short)f2bf(y.z); ha[7] = (short)f2bf(y.w);
            const float4* np0 = reinterpret_cast<const float4*>(out + (size_t)rowc * DIM + k0);
            float4 u = np0[0], v = np0[1];
            na[0] = (short)f2bf(u.x); na[1] = (short)f2bf(u.y);
            na[2] = (short)f2bf(u.z); na[3] = (short)f2bf(u.w);
            na[4] = (short)f2bf(v.x); na[5] = (short)f2bf(v.y);
            na[6] = (short)f2bf(v.z); na[7] = (short)f2bf(v.w);
        }

#pragma unroll
        for (int nt = 0; nt < 8; ++nt) {
            bf16x8 bs = *reinterpret_cast<const bf16x8*>(wpack + (size_t)(((nt * 4 + ks) * 64 + lane) * 8));
            acc[nt] = __builtin_amdgcn_mfma_f32_16x16x32_bf16(ha, bs, acc[nt], 0, 0, 0);
            bf16x8 bn = *reinterpret_cast<const bf16x8*>(wn_p + (size_t)(((nt * 4 + ks) * 64 + lane) * 8));
            acc[nt] = __builtin_amdgcn_mfma_f32_16x16x32_bf16(na, bn, acc[nt], 0, 0, 0);
        }
    }

    // C/D layout (verified m89): col = lane&15, row = (lane>>4)*4 + reg
    const int r0 = node_base + khi * 4;
#pragma unroll
    for (int nt = 0; nt < 8; ++nt) {
        int o = nt * 16 + (lane & 15);
        float bb = bavg[o];
#pragma unroll
        for (int r = 0; r < 4; ++r) {
            int nr = r0 + r;
            if (nr < N_NODES) out[(size_t)nr * DIM + o] = acc[nt][r] + bb;
        }
    }
}

extern "C" void kernel_launch(void* const* d_in, const int* in_sizes, int n_in,
                              void* d_out, int out_size, void* d_ws, size_t ws_size,
                              hipStream_t stream) {
    const float* h  = (const float*)d_in[0];
    const int* src  = (const int*)d_in[1];
    const int* dst  = (const int*)d_in[2];
    const float* Ws = (const float*)d_in[3];
    const float* Wn = (const float*)d_in[4];
    const float* b  = (const float*)d_in[5];
    float* out = (float*)d_out;

    char* ws = (char*)d_ws;
    int* bcur   = (int*)(ws + B_BCUR);
    int* rowoff = (int*)(ws + B_ROWOFF);
    int* csr    = (int*)(ws + B_CSR);
    unsigned short* wpack = (unsigned short*)(ws + B_WPACK);
    float* bavg = (float*)(ws + B_BAVG);
    unsigned short* hb = (unsigned short*)(ws + B_HB);
    int* ebuf   = (int*)d_out;  // padded buckets (12.6MB); dead before gather

    const bool bf = (ws_size >= NEED_BF16);

    hipMemsetAsync(bcur, 0, 256 * sizeof(int), stream);  // relative cursors

    if (bf)
        scatter_prep_kernel<true><<<NBLK + CVT_BLKS, SPT, 0, stream>>>(
            src, dst, bcur, ebuf, h, hb, Ws, Wn, b, wpack, bavg);
    else
        scatter_prep_kernel<false><<<NBLK + 32, SPT, 0, stream>>>(
            src, dst, bcur, ebuf, h, hb, Ws, Wn, b, wpack, bavg);
    csr_build_kernel<<<NB, SPT, 0, stream>>>(bcur, ebuf, rowoff, csr);
    if (bf)
        gather_mean_kernel<true><<<N_NODES / 4, 256, 0, stream>>>(h, hb, rowoff, csr, out);
    else
        gather_mean_kernel<false><<<N_NODES / 4, 256, 0, stream>>>(h, hb, rowoff, csr, out);
    const int gemm_blocks = (N_NODES + 63) / 64;
    if (bf)
        mfma_gemm_kernel<true><<<gemm_blocks, 256, 0, stream>>>(h, hb, out, wpack, bavg);
    else
        mfma_gemm_kernel<false><<<gemm_blocks, 256, 0, stream>>>(h, hb, out, wpack, bavg);
}

// Round 16
// 138.550 us; speedup vs baseline: 1.2872x; 1.0043x over previous
//
#include <hip/hip_runtime.h>

#define N_NODES 100000
#define N_EDGES 1600000
#define DIM 128
#define NH 4

#define NPB 512                                   // nodes per coarse bucket
#define NB 196                                    // buckets
#define CAP 12288                                 // padded bucket capacity (mean 8192)
#define BCHUNK 8192                               // edges per scatter block
#define SPT 512                                   // scatter/prep/csr threads per block
#define BEPT (BCHUNK / SPT)                       // 16
#define NBLK 196                                  // scatter blocks
#define NCHUNK (N_NODES * DIM / 8)                // 1.6M 8-elem conversion chunks
#define NCHALF (NCHUNK / 2)                       // 800000
#define CVT1_BLKS ((NCHALF + SPT - 1) / SPT)      // 1563: chunks [0, NCHALF) w/ scatter
#define CVT2_BLKS ((NCHUNK - NCHALF + SPT - 1) / SPT)  // 1563: rest w/ csr_build

typedef __attribute__((ext_vector_type(8))) short bf16x8;
typedef __attribute__((ext_vector_type(4))) float f32x4;
typedef __attribute__((ext_vector_type(8))) unsigned short u16x8;

// ws layout, BYTE offsets:
//   bcur   : [0, 1024)           int[256] RELATIVE bucket cursors (memset 0)
//   rowoff : [4096, 404096)      int[100000] packed (csr_lo<<9)|deg
//   csr    : [405504, 6805504)   int[1.6M] src ids, dense, bucketed+sorted by dst
//   wpack  : [6805504, 6871040)  bf16 MFMA-packed Ws|Wn
//   bavg   : [6871040, 6871552)  f32[128]
//   hb     : [6871552, 32471552) bf16 copy of h (25.6MB)
// ebuf (padded buckets, 256*CAP ints = 12.6MB) lives in d_out: dead before gather.
#define B_BCUR   0u
#define B_ROWOFF 4096u
#define B_CSR    405504u
#define B_WPACK  6805504u
#define B_BAVG   6871040u
#define B_HB     6871552u
#define NEED_BF16 32869376ull

// branchless RTNE f32->bf16 (finite inputs; no NaN path)
__device__ inline unsigned short f2bf(float x) {
    union { float f; unsigned u; } v; v.f = x;
    unsigned r = v.u + 0x7fffu + ((v.u >> 16) & 1u);
    return (unsigned short)(r >> 16);
}

__device__ inline void cvt_chunk(const float* __restrict__ h,
                                 unsigned short* __restrict__ hb, int i) {
    const float4* p = reinterpret_cast<const float4*>(h) + (size_t)i * 2;
    float4 a = p[0], c = p[1];
    u16x8 r;
    r[0] = f2bf(a.x); r[1] = f2bf(a.y); r[2] = f2bf(a.z); r[3] = f2bf(a.w);
    r[4] = f2bf(c.x); r[5] = f2bf(c.y); r[6] = f2bf(c.z); r[7] = f2bf(c.w);
    reinterpret_cast<u16x8*>(hb)[i] = r;
}

// ---------------------------------------------------------------------------
// Dispatch 1: scatter + prep (weights, bavg, FIRST HALF of h->bf16).
// Blocks [0,NBLK): single-pass bucket scatter (relative cursors). Blocks
// [NBLK,...): weight pack / bavg / conversion chunks [0, NCHALF).
// ---------------------------------------------------------------------------
template <bool BF>
__global__ __launch_bounds__(SPT) void scatter_prep_kernel(
    const int* __restrict__ src, const int* __restrict__ dst,
    int* __restrict__ bcur, int* __restrict__ ebuf,
    const float* __restrict__ h, unsigned short* __restrict__ hb,
    const float* __restrict__ Ws, const float* __restrict__ Wn,
    const float* __restrict__ b, unsigned short* __restrict__ wpack,
    float* __restrict__ bavg) {
    const int t = threadIdx.x;
    if (blockIdx.x >= NBLK) {
        const int pb = blockIdx.x - NBLK;
        const int i = pb * SPT + t;
        if (i < DIM * DIM) {
            float s = 0.f, n = 0.f;
#pragma unroll
            for (int hh = 0; hh < NH; ++hh) {
                s += Ws[hh * DIM * DIM + i];
                n += Wn[hh * DIM * DIM + i];
            }
            s *= 0.25f; n *= 0.25f;
            int k = i >> 7, o = i & 127;
            int nt = o >> 4, lanelo = o & 15;
            int ks = k >> 5, lanehi = (k & 31) >> 3, e = k & 7;
            int pos = (((nt * 4 + ks) * 64) + lanehi * 16 + lanelo) * 8 + e;
            wpack[pos] = f2bf(s);
            wpack[16384 + pos] = f2bf(n);
        }
        if (i < DIM) {
            float bb = 0.f;
#pragma unroll
            for (int hh = 0; hh < NH; ++hh) bb += b[hh * DIM + i];
            bavg[i] = 0.25f * bb;
        }
        if (BF && i < NCHALF) cvt_chunk(h, hb, i);
        return;
    }
    // ---- scatter path (512 threads) ----
    __shared__ int stage[BCHUNK];
    __shared__ unsigned char bkt[BCHUNK];
    __shared__ int lc[256], lbase[256], lpos[256];
    if (t < 256) { lc[t] = 0; lpos[t] = 0; }
    __syncthreads();
    int e0 = blockIdx.x * BCHUNK;
#pragma unroll 4
    for (int j = 0; j < BEPT; ++j) {
        int e = e0 + j * SPT + t;
        if (e < N_EDGES) {
            int d = dst[e];
            stage[j * SPT + t] = (src[e] << 9) | (d & (NPB - 1));
            bkt[j * SPT + t] = (unsigned char)(d >> 9);
            atomicAdd(&lc[d >> 9], 1);
        }
    }
    __syncthreads();
    if (t < 256 && lc[t]) lbase[t] = t * CAP + atomicAdd(&bcur[t], lc[t]);
    __syncthreads();
#pragma unroll 4
    for (int j = 0; j < BEPT; ++j) {
        int e = e0 + j * SPT + t;
        if (e < N_EDGES) {
            int bb = bkt[j * SPT + t];
            int o = atomicAdd(&lpos[bb], 1);
            ebuf[lbase[bb] + o] = stage[j * SPT + t];
        }
    }
}

// ---------------------------------------------------------------------------
// Dispatch 2: csr_build + SECOND HALF of the conversion on otherwise-idle CUs.
// Blocks [0,NB): one block per bucket — internal 256-bucket scan, 512-slot
// hist + scan -> packed rowoff ((lo<<9)|deg), scatter src into dense csr.
// Blocks [NB,...): conversion chunks [NCHALF, NCHUNK). csr_build never touches
// hb, so this parallel filler delays nothing.
// ---------------------------------------------------------------------------
template <bool BF>
__global__ __launch_bounds__(SPT) void csr_build_kernel(
    const int* __restrict__ bcur, const int* __restrict__ ebuf,
    int* __restrict__ rowoff, int* __restrict__ csr,
    const float* __restrict__ h, unsigned short* __restrict__ hb) {
    const int t = threadIdx.x;
    if (blockIdx.x >= NB) {
        if (BF) {
            const int i = NCHALF + (blockIdx.x - NB) * SPT + t;
            if (i < NCHUNK) cvt_chunk(h, hb, i);
        }
        return;
    }
    __shared__ int sh[256];
    __shared__ int hh[NPB], off[NPB], cur[NPB], ss2[NPB];
    const int b = blockIdx.x;
    const int cnt = bcur[b];     // relative count
    const int ibase = b * CAP;
    if (t < 256) sh[t] = bcur[t];
    __syncthreads();
    for (int o = 1; o < 256; o <<= 1) {
        int add = (t < 256 && t >= o) ? sh[t - o] : 0;
        __syncthreads();
        if (t < 256) sh[t] += add;
        __syncthreads();
    }
    const int obase = sh[b] - cnt;
    hh[t] = 0;
    cur[t] = 0;
    __syncthreads();
    for (int i = t; i < cnt; i += SPT) atomicAdd(&hh[ebuf[ibase + i] & (NPB - 1)], 1);
    __syncthreads();
    const int myc = hh[t];
    ss2[t] = myc;
    __syncthreads();
    for (int o = 1; o < NPB; o <<= 1) {
        int add = (t >= o) ? ss2[t - o] : 0;
        __syncthreads();
        ss2[t] += add;
        __syncthreads();
    }
    off[t] = ss2[t] - myc;
    __syncthreads();
    const int n = b * NPB + t;
    if (n < N_NODES) rowoff[n] = ((obase + off[t]) << 9) | min(myc, 511);
    for (int i = t; i < cnt; i += SPT) {
        int p = ebuf[ibase + i];
        int nl = p & (NPB - 1);
        int o = atomicAdd(&cur[nl], 1);
        csr[obase + off[nl] + o] = p >> 9;
    }
}

// ---------------------------------------------------------------------------
// gather-mean (R9/R15 proven config, UNMODIFIED — the 58.7µs floor): 25000
// blocks, one wave per node; 4 edge-slots x 16 lanes x 16B, 2-deep ILP.
// Mean row written as packed bf16 into the FIRST HALF of the node's out row.
// Keep LEAN — no co-compiled heavy paths (R13 lesson).
// ---------------------------------------------------------------------------
template <bool BF>
__global__ __launch_bounds__(256) void gather_mean_kernel(
    const float* __restrict__ h, const unsigned short* __restrict__ hb,
    const int* __restrict__ rowoff, const int* __restrict__ csr,
    float* __restrict__ out) {
    const int node = blockIdx.x * 4 + (threadIdx.x >> 6);
    const int lane = threadIdx.x & 63;
    const int g = lane >> 4;   // edge slot
    const int c = lane & 15;   // 16B chunk within row
    const int w = rowoff[node];
    const int lo = w >> 9, dg = w & 511, hi = lo + dg;
    float a0 = 0.f, a1 = 0.f, a2 = 0.f, a3 = 0.f;
    float a4 = 0.f, a5 = 0.f, a6 = 0.f, a7 = 0.f;
    if (BF) {
        int k = lo + g;
        for (; k + 4 < hi; k += 8) {  // 2 independent row loads in flight
            int s0 = csr[k], s1 = csr[k + 4];
            uint4 v = *reinterpret_cast<const uint4*>(hb + (size_t)s0 * DIM + c * 8);
            uint4 u = *reinterpret_cast<const uint4*>(hb + (size_t)s1 * DIM + c * 8);
            a0 += __uint_as_float(v.x << 16) + __uint_as_float(u.x << 16);
            a1 += __uint_as_float(v.x & 0xffff0000u) + __uint_as_float(u.x & 0xffff0000u);
            a2 += __uint_as_float(v.y << 16) + __uint_as_float(u.y << 16);
            a3 += __uint_as_float(v.y & 0xffff0000u) + __uint_as_float(u.y & 0xffff0000u);
            a4 += __uint_as_float(v.z << 16) + __uint_as_float(u.z << 16);
            a5 += __uint_as_float(v.z & 0xffff0000u) + __uint_as_float(u.z & 0xffff0000u);
            a6 += __uint_as_float(v.w << 16) + __uint_as_float(u.w << 16);
            a7 += __uint_as_float(v.w & 0xffff0000u) + __uint_as_float(u.w & 0xffff0000u);
        }
        if (k < hi) {
            uint4 v = *reinterpret_cast<const uint4*>(hb + (size_t)csr[k] * DIM + c * 8);
            a0 += __uint_as_float(v.x << 16);
            a1 += __uint_as_float(v.x & 0xffff0000u);
            a2 += __uint_as_float(v.y << 16);
            a3 += __uint_as_float(v.y & 0xffff0000u);
            a4 += __uint_as_float(v.z << 16);
            a5 += __uint_as_float(v.z & 0xffff0000u);
            a6 += __uint_as_float(v.w << 16);
            a7 += __uint_as_float(v.w & 0xffff0000u);
        }
    } else {
        for (int k = lo + g; k < hi; k += 4) {
            const float4* p = reinterpret_cast<const float4*>(h + (size_t)csr[k] * DIM + c * 8);
            float4 x = p[0], y = p[1];
            a0 += x.x; a1 += x.y; a2 += x.z; a3 += x.w;
            a4 += y.x; a5 += y.y; a6 += y.z; a7 += y.w;
        }
    }
    a0 += __shfl_xor(a0, 16, 64); a0 += __shfl_xor(a0, 32, 64);
    a1 += __shfl_xor(a1, 16, 64); a1 += __shfl_xor(a1, 32, 64);
    a2 += __shfl_xor(a2, 16, 64); a2 += __shfl_xor(a2, 32, 64);
    a3 += __shfl_xor(a3, 16, 64); a3 += __shfl_xor(a3, 32, 64);
    a4 += __shfl_xor(a4, 16, 64); a4 += __shfl_xor(a4, 32, 64);
    a5 += __shfl_xor(a5, 16, 64); a5 += __shfl_xor(a5, 32, 64);
    a6 += __shfl_xor(a6, 16, 64); a6 += __shfl_xor(a6, 32, 64);
    a7 += __shfl_xor(a7, 16, 64); a7 += __shfl_xor(a7, 32, 64);
    float inv = 1.0f / (float)max(dg, 1);
    if (g == 0) {
        if (BF) {
            u16x8 rr;
            rr[0] = f2bf(a0 * inv); rr[1] = f2bf(a1 * inv);
            rr[2] = f2bf(a2 * inv); rr[3] = f2bf(a3 * inv);
            rr[4] = f2bf(a4 * inv); rr[5] = f2bf(a5 * inv);
            rr[6] = f2bf(a6 * inv); rr[7] = f2bf(a7 * inv);
            *reinterpret_cast<u16x8*>(reinterpret_cast<unsigned short*>(out) +
                                      (size_t)node * 256 + c * 8) = rr;
        } else {
            float4 r0, r1;
            r0.x = a0 * inv; r0.y = a1 * inv; r0.z = a2 * inv; r0.w = a3 * inv;
            r1.x = a4 * inv; r1.y = a5 * inv; r1.z = a6 * inv; r1.w = a7 * inv;
            float4* q = reinterpret_cast<float4*>(out + (size_t)node * DIM + c * 8);
            q[0] = r0;
            q[1] = r1;
        }
    }
}

// ---------------------------------------------------------------------------
// MFMA GEMM (R15 exact): out[n] = h[n]@Ws + hn[n]@Wn + bavg. BF path: ha from
// the bf16 hb copy; hn is packed bf16 in the first half of each out row
// (wave-local in-place overwrite). Wave = 16 nodes x 128 outs, 4 k-steps.
// ---------------------------------------------------------------------------
template <bool BF>
__global__ __launch_bounds__(256) void mfma_gemm_kernel(
    const float* __restrict__ h, const unsigned short* __restrict__ hb,
    float* __restrict__ out, const unsigned short* __restrict__ wpack,
    const float* __restrict__ bavg) {
    const int lane = threadIdx.x & 63;
    const int wid = threadIdx.x >> 6;
    const int node_base = blockIdx.x * 64 + wid * 16;
    const int rowc = min(node_base + (lane & 15), N_NODES - 1);
    const int khi = lane >> 4;

    f32x4 acc[8] = {};
    const unsigned short* wn_p = wpack + 16384;

#pragma unroll
    for (int ks = 0; ks < 4; ++ks) {
        const int k0 = ks * 32 + khi * 8;
        bf16x8 ha, na;
        if (BF) {
            ha = *reinterpret_cast<const bf16x8*>(hb + (size_t)rowc * DIM + k0);
            na = *reinterpret_cast<const bf16x8*>(
                reinterpret_cast<const unsigned short*>(out) + (size_t)rowc * 256 + k0);
        } else {
            const float4* hp = reinterpret_cast<const float4*>(h + (size_t)rowc * DIM + k0);
            float4 x = hp[0], y = hp[1];
            ha[0] = (short)f2bf(x.x); ha[1] = (short)f2bf(x.y);
            ha[2] = (short)f2bf(x.z); ha[3] = (short)f2bf(x.w);
            ha[4] = (short)f2bf(y.x); ha[5] = (short)f2bf(y.y);
            ha[6] = (short)f2bf(y.z); ha[7] = (short)f2bf(y.w);
            const float4* np0 = reinterpret_cast<const float4*>(out + (size_t)rowc * DIM + k0);
            float4 u = np0[0], v = np0[1];
            na[0] = (short)f2bf(u.x); na[1] = (short)f2bf(u.y);
            na[2] = (short)f2bf(u.z); na[3] = (short)f2bf(u.w);
            na[4] = (short)f2bf(v.x); na[5] = (short)f2bf(v.y);
            na[6] = (short)f2bf(v.z); na[7] = (short)f2bf(v.w);
        }

#pragma unroll
        for (int nt = 0; nt < 8; ++nt) {
            bf16x8 bs = *reinterpret_cast<const bf16x8*>(wpack + (size_t)(((nt * 4 + ks) * 64 + lane) * 8));
            acc[nt] = __builtin_amdgcn_mfma_f32_16x16x32_bf16(ha, bs, acc[nt], 0, 0, 0);
            bf16x8 bn = *reinterpret_cast<const bf16x8*>(wn_p + (size_t)(((nt * 4 + ks) * 64 + lane) * 8));
            acc[nt] = __builtin_amdgcn_mfma_f32_16x16x32_bf16(na, bn, acc[nt], 0, 0, 0);
        }
    }

    // C/D layout (verified m89): col = lane&15, row = (lane>>4)*4 + reg
    const int r0 = node_base + khi * 4;
#pragma unroll
    for (int nt = 0; nt < 8; ++nt) {
        int o = nt * 16 + (lane & 15);
        float bb = bavg[o];
#pragma unroll
        for (int r = 0; r < 4; ++r) {
            int nr = r0 + r;
            if (nr < N_NODES) out[(size_t)nr * DIM + o] = acc[nt][r] + bb;
        }
    }
}

extern "C" void kernel_launch(void* const* d_in, const int* in_sizes, int n_in,
                              void* d_out, int out_size, void* d_ws, size_t ws_size,
                              hipStream_t stream) {
    const float* h  = (const float*)d_in[0];
    const int* src  = (const int*)d_in[1];
    const int* dst  = (const int*)d_in[2];
    const float* Ws = (const float*)d_in[3];
    const float* Wn = (const float*)d_in[4];
    const float* b  = (const float*)d_in[5];
    float* out = (float*)d_out;

    char* ws = (char*)d_ws;
    int* bcur   = (int*)(ws + B_BCUR);
    int* rowoff = (int*)(ws + B_ROWOFF);
    int* csr    = (int*)(ws + B_CSR);
    unsigned short* wpack = (unsigned short*)(ws + B_WPACK);
    float* bavg = (float*)(ws + B_BAVG);
    unsigned short* hb = (unsigned short*)(ws + B_HB);
    int* ebuf   = (int*)d_out;  // padded buckets (12.6MB); dead before gather

    const bool bf = (ws_size >= NEED_BF16);

    hipMemsetAsync(bcur, 0, 256 * sizeof(int), stream);  // relative cursors

    if (bf) {
        scatter_prep_kernel<true><<<NBLK + CVT1_BLKS, SPT, 0, stream>>>(
            src, dst, bcur, ebuf, h, hb, Ws, Wn, b, wpack, bavg);
        csr_build_kernel<true><<<NB + CVT2_BLKS, SPT, 0, stream>>>(
            bcur, ebuf, rowoff, csr, h, hb);
        gather_mean_kernel<true><<<N_NODES / 4, 256, 0, stream>>>(h, hb, rowoff, csr, out);
        mfma_gemm_kernel<true><<<(N_NODES + 63) / 64, 256, 0, stream>>>(h, hb, out, wpack, bavg);
    } else {
        scatter_prep_kernel<false><<<NBLK + 32, SPT, 0, stream>>>(
            src, dst, bcur, ebuf, h, hb, Ws, Wn, b, wpack, bavg);
        csr_build_kernel<false><<<NB, SPT, 0, stream>>>(
            bcur, ebuf, rowoff, csr, h, hb);
        gather_mean_kernel<false><<<N_NODES / 4, 256, 0, stream>>>(h, hb, rowoff, csr, out);
        mfma_gemm_kernel<false><<<(N_NODES + 63) / 64, 256, 0, stream>>>(h, hb, out, wpack, bavg);
    }
}